// Round 1
// baseline (524.579 us; speedup 1.0000x reference)
//
#include <hip/hip_runtime.h>
#include <cstdint>
#include <cstddef>

typedef unsigned short u16;
typedef unsigned int u32;

#define NN 50000
#define NE 800000

typedef __attribute__((ext_vector_type(8))) short bf16x8;
typedef __attribute__((ext_vector_type(4))) float f32x4;

__device__ __forceinline__ u16 f2bf(float f) {
  union { float f; u32 i; } v; v.f = f;
  return (u16)((v.i + 0x7FFFu + ((v.i >> 16) & 1u)) >> 16);
}
__device__ __forceinline__ void bf2x2(u32 w, float& a, float& b) {
  union { u32 i; float f; } lo, hi;
  lo.i = w << 16; hi.i = w & 0xFFFF0000u;
  a = lo.f; b = hi.f;
}

// ---------- small prep kernels ----------
__global__ void k_init_f(float* p, int n, float v) {
  int i = blockIdx.x * 256 + threadIdx.x;
  if (i < n) p[i] = v;
}
__global__ void k_init_i(int* p, int n, int v) {
  int i = blockIdx.x * 256 + threadIdx.x;
  if (i < n) p[i] = v;
}
__global__ void k_deg(float* __restrict__ deg, const int* __restrict__ dst,
                      const float* __restrict__ w, int E) {
  int e = blockIdx.x * 256 + threadIdx.x;
  if (e < E) atomicAdd(&deg[dst[e]], w[e]);
}
__global__ void k_dinv(float* __restrict__ dinv, const float* __restrict__ deg, int n) {
  int i = blockIdx.x * 256 + threadIdx.x;
  if (i < n) { float d = deg[i]; dinv[i] = d > 0.f ? rsqrtf(d) : 0.f; }
}
__global__ void k_hist(int* __restrict__ cnt, const int* __restrict__ dst, int E) {
  int e = blockIdx.x * 256 + threadIdx.x;
  if (e < E) atomicAdd(&cnt[dst[e]], 1);
}
__global__ void k_scan_part(const int* __restrict__ cnt, int* __restrict__ bsum, int n) {
  __shared__ int s[256];
  int i = blockIdx.x * 256 + threadIdx.x;
  s[threadIdx.x] = (i < n) ? cnt[i] : 0;
  __syncthreads();
  for (int o = 128; o > 0; o >>= 1) {
    if (threadIdx.x < o) s[threadIdx.x] += s[threadIdx.x + o];
    __syncthreads();
  }
  if (threadIdx.x == 0) bsum[blockIdx.x] = s[0];
}
__global__ void k_scan_mid(const int* __restrict__ bsum, int* __restrict__ bpre, int nb) {
  if (blockIdx.x == 0 && threadIdx.x == 0) {
    int run = 0;
    for (int i = 0; i < nb; i++) { bpre[i] = run; run += bsum[i]; }
  }
}
__global__ void k_scan_fin(const int* __restrict__ cnt, const int* __restrict__ bpre,
                           int* __restrict__ rowptr, int n) {
  __shared__ int s[256];
  int i = blockIdx.x * 256 + threadIdx.x;
  s[threadIdx.x] = (i < n) ? cnt[i] : 0;
  __syncthreads();
  if (threadIdx.x == 0) {
    int run = bpre[blockIdx.x];
    for (int j = 0; j < 256; j++) { int t = s[j]; s[j] = run; run += t; }
  }
  __syncthreads();
  if (i < n) rowptr[i] = s[threadIdx.x];
}
__global__ void k_copy_i(int* __restrict__ d, const int* __restrict__ s, int n) {
  int i = blockIdx.x * 256 + threadIdx.x;
  if (i < n) d[i] = s[i];
}
__global__ void k_fill(const int* __restrict__ src, const int* __restrict__ dst,
                       const float* __restrict__ w, const float* __restrict__ dinv,
                       int* __restrict__ cursor, int* __restrict__ col,
                       float* __restrict__ val, int E) {
  int e = blockIdx.x * 256 + threadIdx.x;
  if (e < E) {
    int d = dst[e], s0 = src[e];
    int p = atomicAdd(&cursor[d], 1);
    col[p] = s0;
    val[p] = dinv[s0] * w[e] * dinv[d];
  }
}
// cast f32 -> bf16, 4 elems/thread
__global__ void k_castx(u16* __restrict__ o, const float* __restrict__ in, int n4) {
  int i = blockIdx.x * 256 + threadIdx.x;
  if (i < n4) {
    float4 f = ((const float4*)in)[i];
    uint2 u;
    u.x = (u32)f2bf(f.x) | ((u32)f2bf(f.y) << 16);
    u.y = (u32)f2bf(f.z) | ((u32)f2bf(f.w) << 16);
    ((uint2*)o)[i] = u;
  }
}
// W [K][Nd] f32 -> Wt [Nd][K] bf16
__global__ void k_wcast(u16* __restrict__ Wt, const float* __restrict__ W, int K, int Nd) {
  int i = blockIdx.x * 256 + threadIdx.x;
  if (i < K * Nd) {
    int k = i / Nd, n = i % Nd;
    Wt[(size_t)n * K + k] = f2bf(W[i]);
  }
}

// ---------- aggregation: out[i] = dinv[i]^2*H[i] + sum_e val*H[col], pull CSR ----------
template <int D, int OUTF32, int RELU, int HASB>
__global__ __launch_bounds__(256) void k_agg(
    const u16* __restrict__ H, const int* __restrict__ rowptr,
    const int* __restrict__ cnt, const int* __restrict__ col,
    const float* __restrict__ val, const float* __restrict__ dinv,
    const float* __restrict__ bias, void* __restrict__ outv) {
  constexpr int V = D / 64;  // elems per lane (4 or 2)
  int wave = threadIdx.x >> 6, lane = threadIdx.x & 63;
  int node = blockIdx.x * 4 + wave;
  if (node >= NN) return;
  const int base = lane * V;
  float acc[V];
  {
    float dv = dinv[node];
    float sw = dv * dv;
    const u16* q = H + (size_t)node * D + base;
    if (V == 4) {
      uint2 u = *(const uint2*)q;
      float a, b, c, d;
      bf2x2(u.x, a, b); bf2x2(u.y, c, d);
      acc[0] = sw * a; acc[1] = sw * b;
      if (V > 2) { acc[V == 4 ? 2 : 0] = sw * c; acc[V == 4 ? 3 : 0] = sw * d; }
    } else {
      u32 u = *(const u32*)q;
      float a, b;
      bf2x2(u, a, b);
      acc[0] = sw * a; acc[1] = sw * b;
    }
  }
  int p = rowptr[node];
  int c0 = cnt[node];
  for (int e = 0; e < c0; e++) {
    int cs = col[p + e];
    float v = val[p + e];
    const u16* q = H + (size_t)cs * D + base;
    if (V == 4) {
      uint2 u = *(const uint2*)q;
      float a, b, c, d;
      bf2x2(u.x, a, b); bf2x2(u.y, c, d);
      acc[0] += v * a; acc[1] += v * b;
      acc[V == 4 ? 2 : 0] += v * c; acc[V == 4 ? 3 : 0] += v * d;
    } else {
      u32 u = *(const u32*)q;
      float a, b;
      bf2x2(u, a, b);
      acc[0] += v * a; acc[1] += v * b;
    }
  }
#pragma unroll
  for (int j = 0; j < V; j++) {
    float v2 = acc[j];
    if (HASB) v2 += bias[base + j];
    if (RELU) v2 = fmaxf(v2, 0.f);
    acc[j] = v2;
  }
  if (OUTF32) {
    float* o = (float*)outv + (size_t)node * D + base;
#pragma unroll
    for (int j = 0; j < V; j++) o[j] = acc[j];
  } else {
    u16* o = (u16*)outv + (size_t)node * D + base;
    if (V == 4) {
      uint2 u;
      u.x = (u32)f2bf(acc[0]) | ((u32)f2bf(acc[1]) << 16);
      u.y = (u32)f2bf(acc[V == 4 ? 2 : 0]) | ((u32)f2bf(acc[V == 4 ? 3 : 0]) << 16);
      *(uint2*)o = u;
    } else {
      *(u32*)o = (u32)f2bf(acc[0]) | ((u32)f2bf(acc[1]) << 16);
    }
  }
}

// ---------- bf16 MFMA GEMM: C[M][Nd] = A[M][K] * Bt[Nd][K]^T (+bias, relu), bf16 out ----------
template <int RELU, int HASB>
__global__ __launch_bounds__(256) void k_gemm(
    const u16* __restrict__ A, const u16* __restrict__ Bt,
    const float* __restrict__ bias, u16* __restrict__ C, int M, int Nd, int K) {
  __shared__ u16 As[128 * 64];
  __shared__ u16 Bs[128 * 64];
  const int tid = threadIdx.x;
  const int wave = tid >> 6, lane = tid & 63;
  const int m0 = blockIdx.x * 128, n0 = blockIdx.y * 128;
  const int wr = wave >> 1, wc = wave & 1;  // 2x2 waves, each 64x64 out
  f32x4 acc[4][4] = {};

  for (int k0 = 0; k0 < K; k0 += 64) {
#pragma unroll
    for (int i = 0; i < 4; i++) {
      int r = i * 32 + wave * 8 + (lane >> 3);
      int rg = m0 + r; rg = rg < M ? rg : M - 1;  // clamp tail rows (outputs masked later)
      const u16* ga = A + (size_t)rg * K + k0 + (lane & 7) * 8;
      __builtin_amdgcn_global_load_lds(
          (const __attribute__((address_space(1))) void*)ga,
          (__attribute__((address_space(3))) void*)&As[(i * 32 + wave * 8) * 64], 16, 0, 0);
      int ng = n0 + r;  // Nd % 128 == 0, no clamp needed
      const u16* gb = Bt + (size_t)ng * K + k0 + (lane & 7) * 8;
      __builtin_amdgcn_global_load_lds(
          (const __attribute__((address_space(1))) void*)gb,
          (__attribute__((address_space(3))) void*)&Bs[(i * 32 + wave * 8) * 64], 16, 0, 0);
    }
    __syncthreads();
#pragma unroll
    for (int kk = 0; kk < 2; kk++) {
      bf16x8 af[4], bfr[4];
#pragma unroll
      for (int mi = 0; mi < 4; mi++)
        af[mi] = *(const bf16x8*)&As[(wr * 64 + mi * 16 + (lane & 15)) * 64 + kk * 32 + (lane >> 4) * 8];
#pragma unroll
      for (int ni = 0; ni < 4; ni++)
        bfr[ni] = *(const bf16x8*)&Bs[(wc * 64 + ni * 16 + (lane & 15)) * 64 + kk * 32 + (lane >> 4) * 8];
#pragma unroll
      for (int mi = 0; mi < 4; mi++)
#pragma unroll
        for (int ni = 0; ni < 4; ni++)
          acc[mi][ni] = __builtin_amdgcn_mfma_f32_16x16x32_bf16(af[mi], bfr[ni], acc[mi][ni], 0, 0, 0);
    }
    __syncthreads();
  }
  // epilogue: D row=(lane>>4)*4+r, col=lane&15 (m89-verified layout)
  const int nb = n0 + wc * 64 + (lane & 15);
  float bv[4];
#pragma unroll
  for (int ni = 0; ni < 4; ni++) bv[ni] = HASB ? bias[nb + ni * 16] : 0.f;
#pragma unroll
  for (int mi = 0; mi < 4; mi++) {
#pragma unroll
    for (int r = 0; r < 4; r++) {
      int row = m0 + wr * 64 + mi * 16 + (lane >> 4) * 4 + r;
      if (row < M) {
#pragma unroll
        for (int ni = 0; ni < 4; ni++) {
          float v = acc[mi][ni][r] + bv[ni];
          if (RELU) v = fmaxf(v, 0.f);
          C[(size_t)row * Nd + nb + ni * 16] = f2bf(v);
        }
      }
    }
  }
}

extern "C" void kernel_launch(void* const* d_in, const int* in_sizes, int n_in,
                              void* d_out, int out_size, void* d_ws, size_t ws_size,
                              hipStream_t stream) {
  const float* x  = (const float*)d_in[0];
  const int*   ei = (const int*)d_in[1];   // [2][NE]: src then dst
  const float* ea = (const float*)d_in[2];
  const float* W1 = (const float*)d_in[3];
  const float* b1 = (const float*)d_in[4];
  const float* W2 = (const float*)d_in[5];
  const float* b2 = (const float*)d_in[6];
  const float* W3 = (const float*)d_in[7];
  const float* b3 = (const float*)d_in[8];
  const int* e_src = ei;
  const int* e_dst = ei + NE;

  // workspace carve (~111 MB total)
  size_t off = 0;
  auto carve = [&](size_t bytes) -> void* {
    void* r = (char*)d_ws + off;
    off += (bytes + 255) & ~(size_t)255;
    return r;
  };
  float* deg    = (float*)carve(NN * 4);
  float* dinv   = (float*)carve(NN * 4);
  int*   counts = (int*)carve(NN * 4);
  int*   rowptr = (int*)carve(NN * 4);
  int*   cursor = (int*)carve(NN * 4);
  int*   bsum   = (int*)carve(256 * 4);
  int*   bpre   = (int*)carve(256 * 4);
  int*   col    = (int*)carve(NE * 4);
  float* valv   = (float*)carve(NE * 4);
  u16*   Wt1    = (u16*)carve(512 * 256 * 2);
  u16*   Wt2    = (u16*)carve(256 * 512 * 2);
  u16*   Wt3    = (u16*)carve(128 * 256 * 2);
  u16*   R0     = (u16*)carve((size_t)NN * 256 * 2);  // x_bf -> t2 -> t3
  u16*   R1     = (u16*)carve((size_t)NN * 256 * 2);  // agg1 -> h2
  u16*   R2     = (u16*)carve((size_t)NN * 512 * 2);  // h1

  const int NB_N = (NN + 255) / 256;   // 196
  const int NB_E = (NE + 255) / 256;   // 3125

  // --- normalization: deg (with self loop weight 1), dinv ---
  k_init_f<<<NB_N, 256, 0, stream>>>(deg, NN, 1.0f);
  k_deg<<<NB_E, 256, 0, stream>>>(deg, e_dst, ea, NE);
  k_dinv<<<NB_N, 256, 0, stream>>>(dinv, deg, NN);

  // --- CSR by dst ---
  k_init_i<<<NB_N, 256, 0, stream>>>(counts, NN, 0);
  k_hist<<<NB_E, 256, 0, stream>>>(counts, e_dst, NE);
  k_scan_part<<<NB_N, 256, 0, stream>>>(counts, bsum, NN);
  k_scan_mid<<<1, 64, 0, stream>>>(bsum, bpre, NB_N);
  k_scan_fin<<<NB_N, 256, 0, stream>>>(counts, bpre, rowptr, NN);
  k_copy_i<<<NB_N, 256, 0, stream>>>(cursor, rowptr, NN);
  k_fill<<<NB_E, 256, 0, stream>>>(e_src, e_dst, ea, dinv, cursor, col, valv, NE);

  // --- casts ---
  k_castx<<<(NN * 256 / 4 + 255) / 256, 256, 0, stream>>>(R0, x, NN * 256 / 4);
  k_wcast<<<(256 * 512 + 255) / 256, 256, 0, stream>>>(Wt1, W1, 256, 512);
  k_wcast<<<(512 * 256 + 255) / 256, 256, 0, stream>>>(Wt2, W2, 512, 256);
  k_wcast<<<(256 * 128 + 255) / 256, 256, 0, stream>>>(Wt3, W3, 256, 128);

  const int AGG_B = NN / 4;  // 12500, 4 waves/block = 4 nodes/block
  dim3 g1((NN + 127) / 128, 512 / 128);
  dim3 g2((NN + 127) / 128, 256 / 128);
  dim3 g3((NN + 127) / 128, 128 / 128);

  // L1: agg1 = A*x ; h1 = relu(agg1*W1 + b1)
  k_agg<256, 0, 0, 0><<<AGG_B, 256, 0, stream>>>(R0, rowptr, counts, col, valv, dinv, nullptr, R1);
  k_gemm<1, 1><<<g1, 256, 0, stream>>>(R1, Wt1, b1, R2, NN, 512, 256);
  // L2: t2 = h1*W2 ; h2 = relu(A*t2 + b2)
  k_gemm<0, 0><<<g2, 256, 0, stream>>>(R2, Wt2, nullptr, R0, NN, 256, 512);
  k_agg<256, 0, 1, 1><<<AGG_B, 256, 0, stream>>>(R0, rowptr, counts, col, valv, dinv, b2, R1);
  // L3: t3 = h2*W3 ; out = A*t3 + b3
  k_gemm<0, 0><<<g3, 256, 0, stream>>>(R1, Wt3, nullptr, R0, NN, 128, 256);
  k_agg<128, 1, 0, 1><<<AGG_B, 256, 0, stream>>>(R0, rowptr, counts, col, valv, dinv, b3, d_out);
}

// Round 3
// 422.597 us; speedup vs baseline: 1.2413x; 1.2413x over previous
//
#include <hip/hip_runtime.h>
#include <cstdint>
#include <cstddef>

typedef unsigned short u16;
typedef unsigned int u32;

#define NN 50000
#define NE 800000

typedef __attribute__((ext_vector_type(8))) short bf16x8;
typedef __attribute__((ext_vector_type(4))) float f32x4;

__device__ __forceinline__ u16 f2bf(float f) {
  union { float f; u32 i; } v; v.f = f;
  return (u16)((v.i + 0x7FFFu + ((v.i >> 16) & 1u)) >> 16);
}
__device__ __forceinline__ void bf2x2(u32 w, float& a, float& b) {
  union { u32 i; float f; } lo, hi;
  lo.i = w << 16; hi.i = w & 0xFFFF0000u;
  a = lo.f; b = hi.f;
}
__device__ __forceinline__ void unpack8(const uint4& q, float* f) {
  bf2x2(q.x, f[0], f[1]); bf2x2(q.y, f[2], f[3]);
  bf2x2(q.z, f[4], f[5]); bf2x2(q.w, f[6], f[7]);
}

// ---------- small prep kernels ----------
__global__ void k_init_i(int* p, int n, int v) {
  int i = blockIdx.x * 256 + threadIdx.x;
  if (i < n) p[i] = v;
}
__global__ void k_dinv(float* __restrict__ dinv, const float* __restrict__ deg, int n) {
  int i = blockIdx.x * 256 + threadIdx.x;
  if (i < n) { float d = deg[i]; dinv[i] = d > 0.f ? rsqrtf(d) : 0.f; }
}
__global__ void k_hist(int* __restrict__ cnt, const int* __restrict__ dst, int E) {
  int e = blockIdx.x * 256 + threadIdx.x;
  if (e < E) atomicAdd(&cnt[dst[e]], 1);
}
__global__ void k_scan_part(const int* __restrict__ cnt, int* __restrict__ bsum, int n) {
  __shared__ int s[256];
  int i = blockIdx.x * 256 + threadIdx.x;
  s[threadIdx.x] = (i < n) ? cnt[i] : 0;
  __syncthreads();
  for (int o = 128; o > 0; o >>= 1) {
    if (threadIdx.x < o) s[threadIdx.x] += s[threadIdx.x + o];
    __syncthreads();
  }
  if (threadIdx.x == 0) bsum[blockIdx.x] = s[0];
}
__global__ void k_scan_mid(const int* __restrict__ bsum, int* __restrict__ bpre, int nb) {
  if (blockIdx.x == 0 && threadIdx.x == 0) {
    int run = 0;
    for (int i = 0; i < nb; i++) { bpre[i] = run; run += bsum[i]; }
  }
}
__global__ void k_scan_fin(const int* __restrict__ cnt, const int* __restrict__ bpre,
                           int* __restrict__ rowptr, int n) {
  __shared__ int s[256];
  int i = blockIdx.x * 256 + threadIdx.x;
  s[threadIdx.x] = (i < n) ? cnt[i] : 0;
  __syncthreads();
  if (threadIdx.x == 0) {
    int run = bpre[blockIdx.x];
    for (int j = 0; j < 256; j++) { int t = s[j]; s[j] = run; run += t; }
  }
  __syncthreads();
  if (i < n) rowptr[i] = s[threadIdx.x];
}
__global__ void k_copy_i(int* __restrict__ d, const int* __restrict__ s, int n) {
  int i = blockIdx.x * 256 + threadIdx.x;
  if (i < n) d[i] = s[i];
}
// edges[p] = (col, w_bits); placement order nondeterministic (sorted later)
__global__ void k_fill(const int* __restrict__ src, const int* __restrict__ dst,
                       const float* __restrict__ w,
                       int* __restrict__ cursor, uint2* __restrict__ edges, int E) {
  int e = blockIdx.x * 256 + threadIdx.x;
  if (e < E) {
    int d = dst[e];
    int p = atomicAdd(&cursor[d], 1);
    uint2 ev;
    ev.x = (u32)src[e];
    ev.y = __float_as_uint(w[e]);
    edges[p] = ev;
  }
}

// one wave per row: bitonic-sort edges[p..p+c) ascending by (col,w_bits),
// then deg[row] = 1 + sum(w) in a fixed reduction order. Fully deterministic.
__global__ __launch_bounds__(256) void k_sortrow(
    uint2* __restrict__ edges, const int* __restrict__ rowptr,
    const int* __restrict__ cnt, float* __restrict__ deg, int n) {
  int wave = threadIdx.x >> 6, lane = threadIdx.x & 63;
  int row = blockIdx.x * 4 + wave;
  if (row >= n) return;
  int p = rowptr[row], c = cnt[row];
  if (c <= 64) {
    u32 kc = 0xFFFFFFFFu, kw = 0xFFFFFFFFu;
    if (lane < c) { uint2 e = edges[p + lane]; kc = e.x; kw = e.y; }
#pragma unroll
    for (int k = 2; k <= 64; k <<= 1) {
#pragma unroll
      for (int j = k >> 1; j > 0; j >>= 1) {
        u32 oc = __shfl_xor(kc, j, 64);
        u32 ow = __shfl_xor(kw, j, 64);
        bool up = ((lane & k) == 0);
        bool lower = ((lane & j) == 0);
        bool gt = (kc > oc) || (kc == oc && kw > ow);
        bool lt = (kc < oc) || (kc == oc && kw < ow);
        bool swap = up ? (lower ? gt : lt) : (lower ? lt : gt);
        if (swap) { kc = oc; kw = ow; }
      }
    }
    float s = (lane < c) ? __uint_as_float(kw) : 0.f;
#pragma unroll
    for (int off = 1; off < 64; off <<= 1) s += __shfl_xor(s, off, 64);
    if (lane < c) { uint2 e; e.x = kc; e.y = kw; edges[p + lane] = e; }
    if (lane == 0) deg[row] = 1.0f + s;
  } else {
    if (lane == 0) {  // rare fallback, deterministic serial insertion sort
      for (int i = 1; i < c; i++) {
        uint2 key = edges[p + i];
        int j2 = i - 1;
        while (j2 >= 0) {
          uint2 a = edges[p + j2];
          bool gt = (a.x > key.x) || (a.x == key.x && a.y > key.y);
          if (!gt) break;
          edges[p + j2 + 1] = a; j2--;
        }
        edges[p + j2 + 1] = key;
      }
      float s = 0.f;
      for (int i = 0; i < c; i++) s += __uint_as_float(edges[p + i].y);
      deg[row] = 1.0f + s;
    }
  }
}

// replace w with norm = dinv[col]*w*dinv[row], in sorted order (deterministic)
__global__ __launch_bounds__(256) void k_val(
    uint2* __restrict__ edges, const int* __restrict__ rowptr,
    const int* __restrict__ cnt, const float* __restrict__ dinv, int n) {
  int wave = threadIdx.x >> 6, lane = threadIdx.x & 63;
  int row = blockIdx.x * 4 + wave;
  if (row >= n) return;
  int p = rowptr[row], c = cnt[row];
  float dr = dinv[row];
  for (int l = lane; l < c; l += 64) {
    uint2 e = edges[p + l];
    float w = __uint_as_float(e.y);
    e.y = __float_as_uint(dinv[(int)e.x] * w * dr);
    edges[p + l] = e;
  }
}

// cast f32 -> bf16, 4 elems/thread
__global__ void k_castx(u16* __restrict__ o, const float* __restrict__ in, int n4) {
  int i = blockIdx.x * 256 + threadIdx.x;
  if (i < n4) {
    float4 f = ((const float4*)in)[i];
    uint2 u;
    u.x = (u32)f2bf(f.x) | ((u32)f2bf(f.y) << 16);
    u.y = (u32)f2bf(f.z) | ((u32)f2bf(f.w) << 16);
    ((uint2*)o)[i] = u;
  }
}
// W [K][Nd] f32 -> Wt [Nd][K] bf16
__global__ void k_wcast(u16* __restrict__ Wt, const float* __restrict__ W, int K, int Nd) {
  int i = blockIdx.x * 256 + threadIdx.x;
  if (i < K * Nd) {
    int k = i / Nd, n = i % Nd;
    Wt[(size_t)n * K + k] = f2bf(W[i]);
  }
}

// ---------- aggregation: out[i] = dinv[i]^2*H[i] + sum_e val*H[col], pull CSR ----------
template <int D, int OUTF32, int RELU, int HASB>
__global__ __launch_bounds__(256) void k_agg(
    const u16* __restrict__ H, const int* __restrict__ rowptr,
    const int* __restrict__ cnt, const uint2* __restrict__ edges,
    const float* __restrict__ dinv,
    const float* __restrict__ bias, void* __restrict__ outv) {
  constexpr int RL = D / 8;     // lanes per row at 16B/lane
  constexpr int EPW = 64 / RL;  // edges in flight per wave
  constexpr int U = 4;
  int wave = threadIdx.x >> 6, lane = threadIdx.x & 63;
  int node = blockIdx.x * 4 + wave;
  if (node >= NN) return;
  const int sub = lane / RL;
  const int rl = lane & (RL - 1);
  const int base = rl * 8;
  float acc[8] = {};
  if (sub == 0) {
    float dv = dinv[node];
    float sw = dv * dv;
    uint4 q = *(const uint4*)(H + (size_t)node * D + base);
    float f[8]; unpack8(q, f);
#pragma unroll
    for (int j = 0; j < 8; j++) acc[j] = sw * f[j];
  }
  const int p = rowptr[node], c = cnt[node];
  for (int e0 = 0; e0 < c; e0 += EPW * U) {
    uint4 q[U];
    float v[U];
#pragma unroll
    for (int u = 0; u < U; u++) {
      int id = e0 + sub + u * EPW;
      bool ok = id < c;
      uint2 ev = edges[p + (ok ? id : 0)];
      v[u] = ok ? __uint_as_float(ev.y) : 0.f;
      int cs = ok ? (int)ev.x : node;
      q[u] = *(const uint4*)(H + (size_t)cs * D + base);
    }
#pragma unroll
    for (int u = 0; u < U; u++) {
      float f[8]; unpack8(q[u], f);
#pragma unroll
      for (int j = 0; j < 8; j++) acc[j] += v[u] * f[j];
    }
  }
#pragma unroll
  for (int j = 0; j < 8; j++) {
#pragma unroll
    for (int off = RL; off < 64; off <<= 1)
      acc[j] += __shfl_xor(acc[j], off, 64);
  }
  if (sub == 0) {
#pragma unroll
    for (int j = 0; j < 8; j++) {
      float v2 = acc[j];
      if (HASB) v2 += bias[base + j];
      if (RELU) v2 = fmaxf(v2, 0.f);
      acc[j] = v2;
    }
    if (OUTF32) {
      float* o = (float*)outv + (size_t)node * D + base;
      float4 f0 = {acc[0], acc[1], acc[2], acc[3]};
      float4 f1 = {acc[4], acc[5], acc[6], acc[7]};
      *(float4*)o = f0;
      *(float4*)(o + 4) = f1;
    } else {
      u16* o = (u16*)outv + (size_t)node * D + base;
      uint4 u;
      u.x = (u32)f2bf(acc[0]) | ((u32)f2bf(acc[1]) << 16);
      u.y = (u32)f2bf(acc[2]) | ((u32)f2bf(acc[3]) << 16);
      u.z = (u32)f2bf(acc[4]) | ((u32)f2bf(acc[5]) << 16);
      u.w = (u32)f2bf(acc[6]) | ((u32)f2bf(acc[7]) << 16);
      *(uint4*)o = u;
    }
  }
}

// ---------- bf16 MFMA GEMM: C[M][Nd] = A[M][K] * Bt[Nd][K]^T (+bias, relu), bf16 out ----------
template <int RELU, int HASB>
__global__ __launch_bounds__(256) void k_gemm(
    const u16* __restrict__ A, const u16* __restrict__ Bt,
    const float* __restrict__ bias, u16* __restrict__ C, int M, int Nd, int K) {
  __shared__ u16 As[128 * 64];
  __shared__ u16 Bs[128 * 64];
  const int tid = threadIdx.x;
  const int wave = tid >> 6, lane = tid & 63;
  const int m0 = blockIdx.x * 128, n0 = blockIdx.y * 128;
  const int wr = wave >> 1, wc = wave & 1;
  f32x4 acc[4][4] = {};

  for (int k0 = 0; k0 < K; k0 += 64) {
#pragma unroll
    for (int i = 0; i < 4; i++) {
      int r = i * 32 + wave * 8 + (lane >> 3);
      int rg = m0 + r; rg = rg < M ? rg : M - 1;
      const u16* ga = A + (size_t)rg * K + k0 + (lane & 7) * 8;
      __builtin_amdgcn_global_load_lds(
          (const __attribute__((address_space(1))) void*)ga,
          (__attribute__((address_space(3))) void*)&As[(i * 32 + wave * 8) * 64], 16, 0, 0);
      int ng = n0 + r;
      const u16* gb = Bt + (size_t)ng * K + k0 + (lane & 7) * 8;
      __builtin_amdgcn_global_load_lds(
          (const __attribute__((address_space(1))) void*)gb,
          (__attribute__((address_space(3))) void*)&Bs[(i * 32 + wave * 8) * 64], 16, 0, 0);
    }
    __syncthreads();
#pragma unroll
    for (int kk = 0; kk < 2; kk++) {
      bf16x8 af[4], bfr[4];
#pragma unroll
      for (int mi = 0; mi < 4; mi++)
        af[mi] = *(const bf16x8*)&As[(wr * 64 + mi * 16 + (lane & 15)) * 64 + kk * 32 + (lane >> 4) * 8];
#pragma unroll
      for (int ni = 0; ni < 4; ni++)
        bfr[ni] = *(const bf16x8*)&Bs[(wc * 64 + ni * 16 + (lane & 15)) * 64 + kk * 32 + (lane >> 4) * 8];
#pragma unroll
      for (int mi = 0; mi < 4; mi++)
#pragma unroll
        for (int ni = 0; ni < 4; ni++)
          acc[mi][ni] = __builtin_amdgcn_mfma_f32_16x16x32_bf16(af[mi], bfr[ni], acc[mi][ni], 0, 0, 0);
    }
    __syncthreads();
  }
  const int nb = n0 + wc * 64 + (lane & 15);
  float bv[4];
#pragma unroll
  for (int ni = 0; ni < 4; ni++) bv[ni] = HASB ? bias[nb + ni * 16] : 0.f;
#pragma unroll
  for (int mi = 0; mi < 4; mi++) {
#pragma unroll
    for (int r = 0; r < 4; r++) {
      int row = m0 + wr * 64 + mi * 16 + (lane >> 4) * 4 + r;
      if (row < M) {
#pragma unroll
        for (int ni = 0; ni < 4; ni++) {
          float v = acc[mi][ni][r] + bv[ni];
          if (RELU) v = fmaxf(v, 0.f);
          C[(size_t)row * Nd + nb + ni * 16] = f2bf(v);
        }
      }
    }
  }
}

extern "C" void kernel_launch(void* const* d_in, const int* in_sizes, int n_in,
                              void* d_out, int out_size, void* d_ws, size_t ws_size,
                              hipStream_t stream) {
  const float* x  = (const float*)d_in[0];
  const int*   ei = (const int*)d_in[1];   // [2][NE]: src then dst
  const float* ea = (const float*)d_in[2];
  const float* W1 = (const float*)d_in[3];
  const float* b1 = (const float*)d_in[4];
  const float* W2 = (const float*)d_in[5];
  const float* b2 = (const float*)d_in[6];
  const float* W3 = (const float*)d_in[7];
  const float* b3 = (const float*)d_in[8];
  const int* e_src = ei;
  const int* e_dst = ei + NE;

  size_t off = 0;
  auto carve = [&](size_t bytes) -> void* {
    void* r = (char*)d_ws + off;
    off += (bytes + 255) & ~(size_t)255;
    return r;
  };
  float* deg    = (float*)carve(NN * 4);
  float* dinv   = (float*)carve(NN * 4);
  int*   counts = (int*)carve(NN * 4);
  int*   rowptr = (int*)carve(NN * 4);
  int*   cursor = (int*)carve(NN * 4);
  int*   bsum   = (int*)carve(256 * 4);
  int*   bpre   = (int*)carve(256 * 4);
  uint2* edges  = (uint2*)carve((size_t)NE * 8);
  u16*   Wt1    = (u16*)carve(512 * 256 * 2);
  u16*   Wt2    = (u16*)carve(256 * 512 * 2);
  u16*   Wt3    = (u16*)carve(128 * 256 * 2);
  u16*   R0     = (u16*)carve((size_t)NN * 256 * 2);  // x_bf -> t2 -> t3
  u16*   R1     = (u16*)carve((size_t)NN * 256 * 2);  // agg1 -> h2
  u16*   R2     = (u16*)carve((size_t)NN * 512 * 2);  // h1

  const int NB_N = (NN + 255) / 256;
  const int NB_E = (NE + 255) / 256;
  const int ROW_B = (NN + 3) / 4;  // 4 rows (waves) per block

  // --- CSR by dst (placement nondeterministic, canonicalized by sort) ---
  k_init_i<<<NB_N, 256, 0, stream>>>(counts, NN, 0);
  k_hist<<<NB_E, 256, 0, stream>>>(counts, e_dst, NE);
  k_scan_part<<<NB_N, 256, 0, stream>>>(counts, bsum, NN);
  k_scan_mid<<<1, 64, 0, stream>>>(bsum, bpre, NB_N);
  k_scan_fin<<<NB_N, 256, 0, stream>>>(counts, bpre, rowptr, NN);
  k_copy_i<<<NB_N, 256, 0, stream>>>(cursor, rowptr, NN);
  k_fill<<<NB_E, 256, 0, stream>>>(e_src, e_dst, ea, cursor, edges, NE);

  // --- canonicalize order, deg, dinv, norm (all deterministic) ---
  k_sortrow<<<ROW_B, 256, 0, stream>>>(edges, rowptr, counts, deg, NN);
  k_dinv<<<NB_N, 256, 0, stream>>>(dinv, deg, NN);
  k_val<<<ROW_B, 256, 0, stream>>>(edges, rowptr, counts, dinv, NN);

  // --- casts ---
  k_castx<<<(NN * 256 / 4 + 255) / 256, 256, 0, stream>>>(R0, x, NN * 256 / 4);
  k_wcast<<<(256 * 512 + 255) / 256, 256, 0, stream>>>(Wt1, W1, 256, 512);
  k_wcast<<<(512 * 256 + 255) / 256, 256, 0, stream>>>(Wt2, W2, 512, 256);
  k_wcast<<<(256 * 128 + 255) / 256, 256, 0, stream>>>(Wt3, W3, 256, 128);

  dim3 g1((NN + 127) / 128, 512 / 128);
  dim3 g2((NN + 127) / 128, 256 / 128);
  dim3 g3((NN + 127) / 128, 128 / 128);

  // L1: agg1 = A*x ; h1 = relu(agg1*W1 + b1)
  k_agg<256, 0, 0, 0><<<ROW_B, 256, 0, stream>>>(R0, rowptr, counts, edges, dinv, nullptr, R1);
  k_gemm<1, 1><<<g1, 256, 0, stream>>>(R1, Wt1, b1, R2, NN, 512, 256);
  // L2: t2 = h1*W2 ; h2 = relu(A*t2 + b2)
  k_gemm<0, 0><<<g2, 256, 0, stream>>>(R2, Wt2, nullptr, R0, NN, 256, 512);
  k_agg<256, 0, 1, 1><<<ROW_B, 256, 0, stream>>>(R0, rowptr, counts, edges, dinv, b2, R1);
  // L3: t3 = h2*W3 ; out = A*t3 + b3
  k_gemm<0, 0><<<g3, 256, 0, stream>>>(R1, Wt3, nullptr, R0, NN, 128, 256);
  k_agg<128, 1, 0, 1><<<ROW_B, 256, 0, stream>>>(R0, rowptr, counts, edges, dinv, b3, d_out);
}

// Round 4
// 412.421 us; speedup vs baseline: 1.2719x; 1.0247x over previous
//
#include <hip/hip_runtime.h>
#include <cstdint>
#include <cstddef>

typedef unsigned short u16;
typedef unsigned int u32;

#define NN 50000
#define NE 800000

typedef __attribute__((ext_vector_type(8))) short bf16x8;
typedef __attribute__((ext_vector_type(4))) float f32x4;

__device__ __forceinline__ u16 f2bf(float f) {
  union { float f; u32 i; } v; v.f = f;
  return (u16)((v.i + 0x7FFFu + ((v.i >> 16) & 1u)) >> 16);
}
__device__ __forceinline__ void bf2x2(u32 w, float& a, float& b) {
  union { u32 i; float f; } lo, hi;
  lo.i = w << 16; hi.i = w & 0xFFFF0000u;
  a = lo.f; b = hi.f;
}
__device__ __forceinline__ void unpack8(const uint4& q, float* f) {
  bf2x2(q.x, f[0], f[1]); bf2x2(q.y, f[2], f[3]);
  bf2x2(q.z, f[4], f[5]); bf2x2(q.w, f[6], f[7]);
}

// ---------- small prep kernels ----------
__global__ void k_hist(int* __restrict__ cnt, const int* __restrict__ dst, int E) {
  int e = blockIdx.x * 256 + threadIdx.x;
  if (e < E) atomicAdd(&cnt[dst[e]], 1);
}
__global__ void k_scan_part(const int* __restrict__ cnt, int* __restrict__ bsum, int n) {
  __shared__ int s[256];
  int i = blockIdx.x * 256 + threadIdx.x;
  s[threadIdx.x] = (i < n) ? cnt[i] : 0;
  __syncthreads();
  for (int o = 128; o > 0; o >>= 1) {
    if (threadIdx.x < o) s[threadIdx.x] += s[threadIdx.x + o];
    __syncthreads();
  }
  if (threadIdx.x == 0) bsum[blockIdx.x] = s[0];
}
__global__ void k_scan_mid(const int* __restrict__ bsum, int* __restrict__ bpre, int nb) {
  if (blockIdx.x == 0 && threadIdx.x == 0) {
    int run = 0;
    for (int i = 0; i < nb; i++) { bpre[i] = run; run += bsum[i]; }
  }
}
__global__ void k_scan_fin(const int* __restrict__ cnt, const int* __restrict__ bpre,
                           int* __restrict__ rowptr, int* __restrict__ cursor, int n) {
  __shared__ int s[256];
  int i = blockIdx.x * 256 + threadIdx.x;
  s[threadIdx.x] = (i < n) ? cnt[i] : 0;
  __syncthreads();
  if (threadIdx.x == 0) {
    int run = bpre[blockIdx.x];
    for (int j = 0; j < 256; j++) { int t = s[j]; s[j] = run; run += t; }
  }
  __syncthreads();
  if (i < n) { rowptr[i] = s[threadIdx.x]; cursor[i] = s[threadIdx.x]; }
}
// edges[p] = (col, w_bits); placement order nondeterministic (sorted later)
__global__ void k_fill(const int* __restrict__ src, const int* __restrict__ dst,
                       const float* __restrict__ w,
                       int* __restrict__ cursor, uint2* __restrict__ edges, int E) {
  int e = blockIdx.x * 256 + threadIdx.x;
  if (e < E) {
    int d = dst[e];
    int p = atomicAdd(&cursor[d], 1);
    uint2 ev;
    ev.x = (u32)src[e];
    ev.y = __float_as_uint(w[e]);
    edges[p] = ev;
  }
}

// one wave per row: bitonic-sort edges[p..p+c) ascending by (col,w_bits),
// then dinv[row] = rsqrt(1 + sum(w)) in a fixed reduction order. Deterministic.
__global__ __launch_bounds__(256) void k_sortrow(
    uint2* __restrict__ edges, const int* __restrict__ rowptr,
    const int* __restrict__ cnt, float* __restrict__ dinv, int n) {
  int wave = threadIdx.x >> 6, lane = threadIdx.x & 63;
  int row = blockIdx.x * 4 + wave;
  if (row >= n) return;
  int p = rowptr[row], c = cnt[row];
  if (c <= 64) {
    u32 kc = 0xFFFFFFFFu, kw = 0xFFFFFFFFu;
    if (lane < c) { uint2 e = edges[p + lane]; kc = e.x; kw = e.y; }
#pragma unroll
    for (int k = 2; k <= 64; k <<= 1) {
#pragma unroll
      for (int j = k >> 1; j > 0; j >>= 1) {
        u32 oc = __shfl_xor(kc, j, 64);
        u32 ow = __shfl_xor(kw, j, 64);
        bool up = ((lane & k) == 0);
        bool lower = ((lane & j) == 0);
        bool gt = (kc > oc) || (kc == oc && kw > ow);
        bool lt = (kc < oc) || (kc == oc && kw < ow);
        bool swap = up ? (lower ? gt : lt) : (lower ? lt : gt);
        if (swap) { kc = oc; kw = ow; }
      }
    }
    float s = (lane < c) ? __uint_as_float(kw) : 0.f;
#pragma unroll
    for (int off = 1; off < 64; off <<= 1) s += __shfl_xor(s, off, 64);
    if (lane < c) { uint2 e; e.x = kc; e.y = kw; edges[p + lane] = e; }
    if (lane == 0) dinv[row] = rsqrtf(1.0f + s);
  } else {
    if (lane == 0) {  // rare fallback, deterministic serial insertion sort
      for (int i = 1; i < c; i++) {
        uint2 key = edges[p + i];
        int j2 = i - 1;
        while (j2 >= 0) {
          uint2 a = edges[p + j2];
          bool gt = (a.x > key.x) || (a.x == key.x && a.y > key.y);
          if (!gt) break;
          edges[p + j2 + 1] = a; j2--;
        }
        edges[p + j2 + 1] = key;
      }
      float s = 0.f;
      for (int i = 0; i < c; i++) s += __uint_as_float(edges[p + i].y);
      dinv[row] = rsqrtf(1.0f + s);
    }
  }
}

// cast f32 -> bf16, 4 elems/thread
__global__ void k_castx(u16* __restrict__ o, const float* __restrict__ in, int n4) {
  int i = blockIdx.x * 256 + threadIdx.x;
  if (i < n4) {
    float4 f = ((const float4*)in)[i];
    uint2 u;
    u.x = (u32)f2bf(f.x) | ((u32)f2bf(f.y) << 16);
    u.y = (u32)f2bf(f.z) | ((u32)f2bf(f.w) << 16);
    ((uint2*)o)[i] = u;
  }
}
// all three weights -> transposed bf16 in one kernel
__global__ void k_wcast3(const float* __restrict__ W1, const float* __restrict__ W2,
                         const float* __restrict__ W3, u16* __restrict__ Wt1,
                         u16* __restrict__ Wt2, u16* __restrict__ Wt3) {
  int i = blockIdx.x * 256 + threadIdx.x;
  if (i < 131072) {                      // W1: [256][512] -> Wt1[512][256]
    int k = i >> 9, n = i & 511;
    Wt1[n * 256 + k] = f2bf(W1[i]);
  } else if (i < 262144) {               // W2: [512][256] -> Wt2[256][512]
    int j = i - 131072;
    int k = j >> 8, n = j & 255;
    Wt2[n * 512 + k] = f2bf(W2[j]);
  } else if (i < 294912) {               // W3: [256][128] -> Wt3[128][256]
    int j = i - 262144;
    int k = j >> 7, n = j & 127;
    Wt3[n * 256 + k] = f2bf(W3[j]);
  }
}

// ---------- aggregation: out[i] = dinv[i]^2*H[i] + sum_e dinv[col]*w*dinv[i]*H[col] ----------
// Edge list (col,w) preloaded into registers (lane l holds edge l), per-edge data
// via __shfl; U*EPW gathers kept in flight. Rare deg>64 tail handled directly.
template <int D, int OUTF32, int RELU, int HASB, int U>
__global__ __launch_bounds__(256) void k_agg(
    const u16* __restrict__ H, const int* __restrict__ rowptr,
    const int* __restrict__ cnt, const uint2* __restrict__ edges,
    const float* __restrict__ dinv,
    const float* __restrict__ bias, void* __restrict__ outv) {
  constexpr int RL = D / 8;     // lanes per row at 16B/lane
  constexpr int EPW = 64 / RL;  // edges per wave per slot
  int wave = threadIdx.x >> 6, lane = threadIdx.x & 63;
  int node = blockIdx.x * 4 + wave;
  if (node >= NN) return;
  const int sub = lane / RL;
  const int rl = lane & (RL - 1);
  const int base = rl * 8;
  const int p = rowptr[node], c = cnt[node];
  const float dvr = dinv[node];
  // preload first 64 edges into registers (one 8B load per lane)
  u32 ecol, ewv;
  {
    bool has = lane < c;
    uint2 e0;
    if (has) e0 = edges[p + lane];
    else { e0.x = (u32)node; e0.y = 0u; }
    ecol = e0.x; ewv = e0.y;
  }
  const int cl = c < 64 ? c : 64;
  float acc[8] = {};
  if (sub == 0) {
    float sw = dvr * dvr;
    uint4 q = *(const uint4*)(H + (size_t)node * D + base);
    float f[8]; unpack8(q, f);
#pragma unroll
    for (int j = 0; j < 8; j++) acc[j] = sw * f[j];
  }
  for (int e0 = 0; e0 < cl; e0 += EPW * U) {
    uint4 q[U];
    float v[U];
#pragma unroll
    for (int u = 0; u < U; u++) {
      int id = e0 + sub + u * EPW;
      bool ok = id < cl;
      int idc = ok ? id : 63;
      u32 cc = __shfl(ecol, idc, 64);
      u32 ww = __shfl(ewv, idc, 64);
      int cs = ok ? (int)cc : node;
      float dvc = dinv[cs];
      v[u] = ok ? dvc * __uint_as_float(ww) * dvr : 0.f;
      q[u] = *(const uint4*)(H + (size_t)cs * D + base);
    }
#pragma unroll
    for (int u = 0; u < U; u++) {
      float f[8]; unpack8(q[u], f);
#pragma unroll
      for (int j = 0; j < 8; j++) acc[j] += v[u] * f[j];
    }
  }
  // rare overflow tail (deg > 64)
  for (int id = 64 + sub; id < c; id += EPW) {
    uint2 ev = edges[p + id];
    int cs = (int)ev.x;
    float v = dinv[cs] * __uint_as_float(ev.y) * dvr;
    uint4 q = *(const uint4*)(H + (size_t)cs * D + base);
    float f[8]; unpack8(q, f);
#pragma unroll
    for (int j = 0; j < 8; j++) acc[j] += v * f[j];
  }
  // combine sub-wave partials
#pragma unroll
  for (int j = 0; j < 8; j++) {
#pragma unroll
    for (int off = RL; off < 64; off <<= 1)
      acc[j] += __shfl_xor(acc[j], off, 64);
  }
  if (sub == 0) {
#pragma unroll
    for (int j = 0; j < 8; j++) {
      float v2 = acc[j];
      if (HASB) v2 += bias[base + j];
      if (RELU) v2 = fmaxf(v2, 0.f);
      acc[j] = v2;
    }
    if (OUTF32) {
      float* o = (float*)outv + (size_t)node * D + base;
      float4 f0 = {acc[0], acc[1], acc[2], acc[3]};
      float4 f1 = {acc[4], acc[5], acc[6], acc[7]};
      *(float4*)o = f0;
      *(float4*)(o + 4) = f1;
    } else {
      u16* o = (u16*)outv + (size_t)node * D + base;
      uint4 u;
      u.x = (u32)f2bf(acc[0]) | ((u32)f2bf(acc[1]) << 16);
      u.y = (u32)f2bf(acc[2]) | ((u32)f2bf(acc[3]) << 16);
      u.z = (u32)f2bf(acc[4]) | ((u32)f2bf(acc[5]) << 16);
      u.w = (u32)f2bf(acc[6]) | ((u32)f2bf(acc[7]) << 16);
      *(uint4*)o = u;
    }
  }
}

// ---------- bf16 MFMA GEMM: C[M][Nd] = A[M][K] * Bt[Nd][K]^T (+bias, relu), bf16 out ----------
template <int RELU, int HASB>
__global__ __launch_bounds__(256) void k_gemm(
    const u16* __restrict__ A, const u16* __restrict__ Bt,
    const float* __restrict__ bias, u16* __restrict__ C, int M, int Nd, int K) {
  __shared__ u16 As[128 * 64];
  __shared__ u16 Bs[128 * 64];
  const int tid = threadIdx.x;
  const int wave = tid >> 6, lane = tid & 63;
  const int m0 = blockIdx.x * 128, n0 = blockIdx.y * 128;
  const int wr = wave >> 1, wc = wave & 1;
  f32x4 acc[4][4] = {};

  for (int k0 = 0; k0 < K; k0 += 64) {
#pragma unroll
    for (int i = 0; i < 4; i++) {
      int r = i * 32 + wave * 8 + (lane >> 3);
      int rg = m0 + r; rg = rg < M ? rg : M - 1;
      const u16* ga = A + (size_t)rg * K + k0 + (lane & 7) * 8;
      __builtin_amdgcn_global_load_lds(
          (const __attribute__((address_space(1))) void*)ga,
          (__attribute__((address_space(3))) void*)&As[(i * 32 + wave * 8) * 64], 16, 0, 0);
      int ng = n0 + r;
      const u16* gb = Bt + (size_t)ng * K + k0 + (lane & 7) * 8;
      __builtin_amdgcn_global_load_lds(
          (const __attribute__((address_space(1))) void*)gb,
          (__attribute__((address_space(3))) void*)&Bs[(i * 32 + wave * 8) * 64], 16, 0, 0);
    }
    __syncthreads();
#pragma unroll
    for (int kk = 0; kk < 2; kk++) {
      bf16x8 af[4], bfr[4];
#pragma unroll
      for (int mi = 0; mi < 4; mi++)
        af[mi] = *(const bf16x8*)&As[(wr * 64 + mi * 16 + (lane & 15)) * 64 + kk * 32 + (lane >> 4) * 8];
#pragma unroll
      for (int ni = 0; ni < 4; ni++)
        bfr[ni] = *(const bf16x8*)&Bs[(wc * 64 + ni * 16 + (lane & 15)) * 64 + kk * 32 + (lane >> 4) * 8];
#pragma unroll
      for (int mi = 0; mi < 4; mi++)
#pragma unroll
        for (int ni = 0; ni < 4; ni++)
          acc[mi][ni] = __builtin_amdgcn_mfma_f32_16x16x32_bf16(af[mi], bfr[ni], acc[mi][ni], 0, 0, 0);
    }
    __syncthreads();
  }
  const int nb = n0 + wc * 64 + (lane & 15);
  float bv[4];
#pragma unroll
  for (int ni = 0; ni < 4; ni++) bv[ni] = HASB ? bias[nb + ni * 16] : 0.f;
#pragma unroll
  for (int mi = 0; mi < 4; mi++) {
#pragma unroll
    for (int r = 0; r < 4; r++) {
      int row = m0 + wr * 64 + mi * 16 + (lane >> 4) * 4 + r;
      if (row < M) {
#pragma unroll
        for (int ni = 0; ni < 4; ni++) {
          float v = acc[mi][ni][r] + bv[ni];
          if (RELU) v = fmaxf(v, 0.f);
          C[(size_t)row * Nd + nb + ni * 16] = f2bf(v);
        }
      }
    }
  }
}

extern "C" void kernel_launch(void* const* d_in, const int* in_sizes, int n_in,
                              void* d_out, int out_size, void* d_ws, size_t ws_size,
                              hipStream_t stream) {
  const float* x  = (const float*)d_in[0];
  const int*   ei = (const int*)d_in[1];   // [2][NE]: src then dst
  const float* ea = (const float*)d_in[2];
  const float* W1 = (const float*)d_in[3];
  const float* b1 = (const float*)d_in[4];
  const float* W2 = (const float*)d_in[5];
  const float* b2 = (const float*)d_in[6];
  const float* W3 = (const float*)d_in[7];
  const float* b3 = (const float*)d_in[8];
  const int* e_src = ei;
  const int* e_dst = ei + NE;

  size_t off = 0;
  auto carve = [&](size_t bytes) -> void* {
    void* r = (char*)d_ws + off;
    off += (bytes + 255) & ~(size_t)255;
    return r;
  };
  float* dinv   = (float*)carve(NN * 4);
  int*   counts = (int*)carve(NN * 4);
  int*   rowptr = (int*)carve(NN * 4);
  int*   cursor = (int*)carve(NN * 4);
  int*   bsum   = (int*)carve(256 * 4);
  int*   bpre   = (int*)carve(256 * 4);
  uint2* edges  = (uint2*)carve((size_t)NE * 8);
  u16*   Wt1    = (u16*)carve(512 * 256 * 2);
  u16*   Wt2    = (u16*)carve(256 * 512 * 2);
  u16*   Wt3    = (u16*)carve(128 * 256 * 2);
  u16*   R0     = (u16*)carve((size_t)NN * 256 * 2);  // x_bf -> t2 -> t3
  u16*   R1     = (u16*)carve((size_t)NN * 256 * 2);  // agg1 -> h2
  u16*   R2     = (u16*)carve((size_t)NN * 512 * 2);  // h1

  const int NB_N = (NN + 255) / 256;
  const int NB_E = (NE + 255) / 256;
  const int ROW_B = (NN + 3) / 4;  // 4 rows (waves) per block

  // --- CSR by dst (placement nondeterministic, canonicalized by sort) ---
  hipMemsetAsync(counts, 0, (size_t)NN * 4, stream);
  k_hist<<<NB_E, 256, 0, stream>>>(counts, e_dst, NE);
  k_scan_part<<<NB_N, 256, 0, stream>>>(counts, bsum, NN);
  k_scan_mid<<<1, 64, 0, stream>>>(bsum, bpre, NB_N);
  k_scan_fin<<<NB_N, 256, 0, stream>>>(counts, bpre, rowptr, cursor, NN);
  k_fill<<<NB_E, 256, 0, stream>>>(e_src, e_dst, ea, cursor, edges, NE);
  k_sortrow<<<ROW_B, 256, 0, stream>>>(edges, rowptr, counts, dinv, NN);

  // --- casts ---
  k_castx<<<(NN * 256 / 4 + 255) / 256, 256, 0, stream>>>(R0, x, NN * 256 / 4);
  k_wcast3<<<(294912 + 255) / 256, 256, 0, stream>>>(W1, W2, W3, Wt1, Wt2, Wt3);

  dim3 g1((NN + 127) / 128, 512 / 128);
  dim3 g2((NN + 127) / 128, 256 / 128);
  dim3 g3((NN + 127) / 128, 128 / 128);

  // L1: agg1 = A*x ; h1 = relu(agg1*W1 + b1)
  k_agg<256, 0, 0, 0, 6><<<ROW_B, 256, 0, stream>>>(R0, rowptr, counts, edges, dinv, nullptr, R1);
  k_gemm<1, 1><<<g1, 256, 0, stream>>>(R1, Wt1, b1, R2, NN, 512, 256);
  // L2: t2 = h1*W2 ; h2 = relu(A*t2 + b2)
  k_gemm<0, 0><<<g2, 256, 0, stream>>>(R2, Wt2, nullptr, R0, NN, 256, 512);
  k_agg<256, 0, 1, 1, 6><<<ROW_B, 256, 0, stream>>>(R0, rowptr, counts, edges, dinv, b2, R1);
  // L3: t3 = h2*W3 ; out = A*t3 + b3
  k_gemm<0, 0><<<g3, 256, 0, stream>>>(R1, Wt3, nullptr, R0, NN, 128, 256);
  k_agg<128, 1, 0, 1, 6><<<ROW_B, 256, 0, stream>>>(R0, rowptr, counts, edges, dinv, b3, d_out);
}